// Round 12
// baseline (607.739 us; speedup 1.0000x reference)
//
#include <hip/hip_runtime.h>
#include <hip/hip_bf16.h>

// MultiHeadAttention: B=4, N=2048, D=1024, H=16, HD=64, causal.
// Contract: f32 inputs AND f32 output; bf16 internal compute.
// R21 = R20 flash (kept; left top-5) + QKV GEMM restructured:
//  - gemm_qkv: 256x128 tile, 512 thr (8 waves = 4m x 2n), grid (32,8,3) =
//    768 blocks = exactly 3/CU (LDS 34816 -> 4-slot capacity, slack for
//    skew). Kills the 4-then-2 residency tail (was 1536 blocks = 6/CU over
//    4 slots): 24 waves/CU throughout. B-panel staged once per 256 rows ->
//    operand FETCH -25%. Inner loop = proven BK=32 structure unchanged.
//  - Epilogue: two 128-row passes through Cs[128x136] (stage waves
//    wm>>1==pp, all threads store). VGPR pinned by launch_bounds(512,6)
//    (cap ~85; inner loop measured 80 at 128^2). Spill -> WRITE_SIZE blows
//    up -> revert next round.
//  - gemm_bt<1> (out-proj) unchanged: 512 blocks already single-round.

#define BB 4
#define NN 2048
#define DD 1024
#define HH 16
#define HD 64
#define MM (BB * NN) // 8192

typedef __bf16 bf16;
typedef __bf16 bf16x4 __attribute__((ext_vector_type(4)));
typedef __bf16 bf16x8 __attribute__((ext_vector_type(8)));
typedef float f32x4 __attribute__((ext_vector_type(4)));

// Async 16B global->LDS copy. LDS dest must follow wave-uniform base + lane*16.
__device__ __forceinline__ void async_copy16(bf16* lds, const bf16* g) {
    __builtin_amdgcn_global_load_lds(
        (const __attribute__((address_space(1))) void*)g,
        (__attribute__((address_space(3))) void*)lds, 16, 0, 0);
}

// ---------------------------------------------------------------------------
// prep: fused input conversion + weight transpose (one dispatch, z = role).
// ---------------------------------------------------------------------------
__global__ void prep(const float* __restrict__ x,
                     const float* __restrict__ W0, const float* __restrict__ W1,
                     const float* __restrict__ W2, const float* __restrict__ W3,
                     bf16* __restrict__ xb, bf16* __restrict__ Wt) {
    __shared__ float tile[32][33];
    if (blockIdx.z == 0) {
        int i = (blockIdx.x * 256 + threadIdx.x) * 8;
        float4 a = *(const float4*)&x[i];
        float4 b = *(const float4*)&x[i + 4];
        bf16x8 o;
        o[0] = (bf16)a.x; o[1] = (bf16)a.y; o[2] = (bf16)a.z; o[3] = (bf16)a.w;
        o[4] = (bf16)b.x; o[5] = (bf16)b.y; o[6] = (bf16)b.z; o[7] = (bf16)b.w;
        *(bf16x8*)&xb[i] = o;
    } else {
        int wz = blockIdx.x >> 10;            // 0..3
        int by = (blockIdx.x >> 5) & 31;
        int bx = blockIdx.x & 31;
        const float* W = (wz == 0) ? W0 : (wz == 1) ? W1 : (wz == 2) ? W2 : W3;
        bf16* out = Wt + (size_t)wz * DD * DD;
        int tx = threadIdx.x & 31, ty = threadIdx.x >> 5; // 32 x 8
        int x0 = bx * 32, y0 = by * 32;
#pragma unroll
        for (int i = 0; i < 32; i += 8)
            tile[ty + i][tx] = W[(size_t)(y0 + ty + i) * DD + x0 + tx];
        __syncthreads();
#pragma unroll
        for (int i = 0; i < 32; i += 8)
            out[(size_t)(x0 + ty + i) * DD + y0 + tx] = (bf16)tile[tx][ty + i];
    }
}

// ---------------------------------------------------------------------------
// gemm_qkv: C[256x128 tile] = A[M,K] * Wt[N,K]^T + bias, bf16 MFMA, BK=32.
// 512 threads = 8 waves in 4(m) x 2(n); each wave 64x64 (4x4 MFMA 16x16x32).
// grid (32, 8, 3): z selects Q/K/V. Q scaled by 0.125*log2e.
// z==0/1: bf16 out [B*H, N, HD]; z==2: V^T out [B*H, HD, N], kv-permuted
// per-32-tok: pos p <- orig o(p) = (p>>3)*4 + ((p>>2)&1)*16 + (p&3).
// Epilogue: two 128-row passes via Cs[128][136] (aliased over As/Bs).
// ---------------------------------------------------------------------------
__global__ __launch_bounds__(512, 6) void gemm_qkv(
    const bf16* __restrict__ A, const bf16* __restrict__ Wt,
    const float* __restrict__ b0, const float* __restrict__ b1,
    const float* __restrict__ b2, bf16* __restrict__ out0,
    bf16* __restrict__ out1, bf16* __restrict__ out2) {
    const int K = DD;
    // Union: K-loop uses As(8192 elems) + Bs(4096); epilogue uses Cs(17408).
    __shared__ __align__(16) bf16 smem[128 * 136];
    bf16* As = smem;               // [256][32]
    bf16* Bs = smem + 256 * 32;    // [128][32]
    bf16* Cs = smem;               // epilogue alias, [128][136]

    int m0 = blockIdx.x * 256;
    int n0 = blockIdx.y * 128;
    int z = blockIdx.z;
    const bf16* Wz = Wt + (size_t)z * DD * DD;
    const float* bias = (z == 0) ? b0 : ((z == 1) ? b1 : b2);
    bf16* out = (z == 0) ? out0 : ((z == 1) ? out1 : out2);
    float scale = (z == 0) ? 0.125f * 1.44269504f : 1.0f;

    int tid = threadIdx.x;
    int w = tid >> 6, lane = tid & 63;
    int wm = w >> 1, wn = w & 1;          // wm 0..3, wn 0..1
    int quad = lane >> 4, l16 = lane & 15;

    f32x4 acc[4][4];
#pragma unroll
    for (int i = 0; i < 4; i++)
#pragma unroll
        for (int j = 0; j < 4; j++) acc[i][j] = (f32x4){0.f, 0.f, 0.f, 0.f};

    for (int k0 = 0; k0 < K; k0 += 32) {
        __syncthreads(); // previous iteration's LDS reads complete
        // A: 1024 chunks (2/thread); B: 512 chunks (1/thread). Linear dests.
#pragma unroll
        for (int j = 0; j < 2; j++) {
            int c = j * 512 + tid;
            int row = c >> 2, kk = (c & 3) * 8;
            async_copy16(&As[c * 8], &A[(size_t)(m0 + row) * K + k0 + kk]);
        }
        {
            int row = tid >> 2, kk = (tid & 3) * 8;
            async_copy16(&Bs[tid * 8], &Wz[(size_t)(n0 + row) * K + k0 + kk]);
        }
        __syncthreads(); // drains vmcnt(0) before barrier

        bf16x8 af[4], bfm[4];
#pragma unroll
        for (int i = 0; i < 4; i++) {
            af[i] = *(const bf16x8*)&As[(wm * 64 + i * 16 + l16) * 32 + quad * 8];
            bfm[i] = *(const bf16x8*)&Bs[(wn * 64 + i * 16 + l16) * 32 + quad * 8];
        }
#pragma unroll
        for (int i = 0; i < 4; i++)
#pragma unroll
            for (int j = 0; j < 4; j++)
                acc[i][j] = __builtin_amdgcn_mfma_f32_16x16x32_bf16(
                    af[i], bfm[j], acc[i][j], 0, 0, 0);
    }

    // Epilogue. C/D layout: col(n) = l16, row(m) = quad*4 + reg.
    int bidx = m0 >> 11;          // batch (256-row tile never crosses batch)
    int tok0 = m0 & (NN - 1);
    int hh0 = n0 >> 6;            // first of the 2 heads this tile covers
    __syncthreads();              // all waves' As/Bs reads done

#pragma unroll
    for (int pp = 0; pp < 2; pp++) {
        if (pp) __syncthreads();  // previous pass's stores done before restage
        // Stage: waves with wm>>1 == pp hold rows pp*128 .. pp*128+127.
        if ((wm >> 1) == pp) {
#pragma unroll
            for (int j = 0; j < 4; j++) {
                int nl = wn * 64 + j * 16 + l16;
                float bv = bias[n0 + nl];
#pragma unroll
                for (int i = 0; i < 4; i++) {
#pragma unroll
                    for (int r = 0; r < 4; r++) {
                        int mloc = (wm & 1) * 64 + i * 16 + quad * 4 + r; // 0..127
                        bf16 v = (bf16)((acc[i][j][r] + bv) * scale);
                        if (z == 2) Cs[nl * 136 + mloc] = v;
                        else        Cs[mloc * 136 + nl] = v;
                    }
                }
            }
        }
        __syncthreads();

        if (z != 2) {
            // out [bh][tok][hd]: tokens tok0+pp*128..+128, both heads.
#pragma unroll
            for (int hf = 0; hf < 2; hf++) {
                bf16* base = out +
                    ((size_t)(bidx * HH + hh0 + hf) * NN + tok0 + pp * 128) * HD;
#pragma unroll
                for (int k = 0; k < 2; k++) {
                    int f = k * 4096 + tid * 8;       // 0..8191; tok=f>>6, hd=f&63
                    *(bf16x8*)&base[f] =
                        *(const bf16x8*)&Cs[(f >> 6) * 136 + hf * 64 + (f & 63)];
                }
            }
        } else {
            // V^T out [bh][hd][tok], kv-permuted per 32-tok block.
#pragma unroll
            for (int k = 0; k < 4; k++) {
                int idx = k * 4096 + tid * 8;         // 0..16383
                int nl = idx >> 7;                    // 0..127
                int p0 = idx & 127;                   // 8-aligned
                int hf = nl >> 6, hd = nl & 63;
                int base32 = p0 & ~31;
                int qq = (p0 & 31) >> 3;
                const bf16* crow = &Cs[nl * 136];
                bf16x4 lo = *(const bf16x4*)&crow[base32 + qq * 4];
                bf16x4 hi = *(const bf16x4*)&crow[base32 + qq * 4 + 16];
                bf16x8 v = __builtin_shufflevector(lo, hi, 0, 1, 2, 3, 4, 5, 6, 7);
                bf16* dst = out +
                    ((size_t)(bidx * HH + hh0 + hf) * HD + hd) * NN +
                    tok0 + pp * 128 + p0;
                *(bf16x8*)dst = v;
            }
        }
    }
}

// ---------------------------------------------------------------------------
// gemm_out: out-projection, f32 output, plain [M, N]. 128x128 tile, 4 waves,
// BK=32 (unchanged measured-best structure; 512 blocks = single-round).
// ---------------------------------------------------------------------------
__global__ __launch_bounds__(256) void gemm_out(
    const bf16* __restrict__ A, const bf16* __restrict__ Wt,
    const float* __restrict__ bias, float* __restrict__ out) {
    const int K = DD;
    __shared__ __align__(16) bf16 smem[128 * 64];
    bf16* As = smem;
    bf16* Bs = smem + 128 * 32;

    int m0 = blockIdx.x * 128;
    int n0 = blockIdx.y * 128;

    int tid = threadIdx.x;
    int w = tid >> 6, lane = tid & 63;
    int wm = w >> 1, wn = w & 1;
    int quad = lane >> 4, l16 = lane & 15;

    f32x4 acc[4][4];
#pragma unroll
    for (int i = 0; i < 4; i++)
#pragma unroll
        for (int j = 0; j < 4; j++) acc[i][j] = (f32x4){0.f, 0.f, 0.f, 0.f};

    for (int k0 = 0; k0 < K; k0 += 32) {
        __syncthreads();
#pragma unroll
        for (int j = 0; j < 2; j++) {
            int c = j * 256 + w * 64 + lane;
            int row = c >> 2, kk = (c & 3) * 8;
            async_copy16(&As[c * 8], &A[(size_t)(m0 + row) * K + k0 + kk]);
            async_copy16(&Bs[c * 8], &Wt[(size_t)(n0 + row) * K + k0 + kk]);
        }
        __syncthreads();

        bf16x8 af[4], bfm[4];
#pragma unroll
        for (int i = 0; i < 4; i++) {
            af[i] = *(const bf16x8*)&As[(wm * 64 + i * 16 + l16) * 32 + quad * 8];
            bfm[i] = *(const bf16x8*)&Bs[(wn * 64 + i * 16 + l16) * 32 + quad * 8];
        }
#pragma unroll
        for (int i = 0; i < 4; i++)
#pragma unroll
            for (int j = 0; j < 4; j++)
                acc[i][j] = __builtin_amdgcn_mfma_f32_16x16x32_bf16(
                    af[i], bfm[j], acc[i][j], 0, 0, 0);
    }

#pragma unroll
    for (int j = 0; j < 4; j++) {
        int n = n0 + wn * 64 + j * 16 + l16;
        float bv = bias[n];
#pragma unroll
        for (int i = 0; i < 4; i++) {
            int mrow = m0 + wm * 64 + i * 16 + quad * 4;
#pragma unroll
            for (int r = 0; r < 4; r++)
                out[(size_t)(mrow + r) * DD + n] = acc[i][j][r] + bv;
        }
    }
}

// ---------------------------------------------------------------------------
// Flash attention (causal, no-max softmax) — R20 (kept): fine-grained blocks.
// grid = (B*H, 16), block = 256 threads (4 waves x 16 q-rows = 64-row q-tile).
// bh on blockIdx.x -> linear id%8 == bh%8 -> XCD L2 affinity for K/V.
// Block does q-tiles j=blockIdx.y and 31-blockIdx.y: 33 kv-iters per block;
// 1024 blocks x 36864B LDS = exactly 4/CU (4 independent barrier domains).
// ---------------------------------------------------------------------------
__global__ __launch_bounds__(256, 4) void flash_attn(
    const bf16* __restrict__ Q, const bf16* __restrict__ Kg,
    const bf16* __restrict__ Vt_g, bf16* __restrict__ Oc) {
    __shared__ __align__(16) bf16 Ks[2][64 * 72];   // [kv][hd], stride 72
    __shared__ __align__(16) bf16 Vs[2][64 * 72];   // [d][kv-perm], stride 72

    int bh = blockIdx.x;              // linear id % 8 == bh % 8 -> XCD locality
    int b = bh >> 4, h = bh & 15;
    int tid = threadIdx.x;
    int w = tid >> 6, lane = tid & 63;
    int quad = lane >> 4, l16 = lane & 15;

    const bf16* Qb = Q + (size_t)bh * NN * HD;
    const bf16* Kb = Kg + (size_t)bh * NN * HD;
    const bf16* Vtb = Vt_g + (size_t)bh * HD * NN;

    bf16x8 ones8;
#pragma unroll
    for (int i = 0; i < 8; i++) ones8[i] = (bf16)1.0f;

    int kr[2], kc[2];
#pragma unroll
    for (int j = 0; j < 2; j++) {
        int c = j * 256 + tid;
        kr[j] = c >> 3; kc[j] = (c & 7) * 8;   // row 0..63, col-chunk
    }

    for (int phase = 0; phase < 2; phase++) {
        int qj = (phase == 0) ? blockIdx.y : (31 - blockIdx.y);
        int q0 = qj * 64;
        int qrow = q0 + w * 16 + l16;

        bf16x8 qf[2];
#pragma unroll
        for (int ks = 0; ks < 2; ks++)
            qf[ks] = *(const bf16x8*)&Qb[(size_t)qrow * HD + ks * 32 + quad * 8];

        f32x4 l_sum = (f32x4){0.f, 0.f, 0.f, 0.f};
        f32x4 o_acc[4];
#pragma unroll
        for (int di = 0; di < 4; di++) o_acc[di] = (f32x4){0.f, 0.f, 0.f, 0.f};

        bf16x8 kreg[2], vreg[2];
#pragma unroll
        for (int j = 0; j < 2; j++) {
            kreg[j] = *(const bf16x8*)&Kb[(size_t)kr[j] * HD + kc[j]];
            vreg[j] = *(const bf16x8*)&Vtb[(size_t)kr[j] * NN + kc[j]];
        }
#pragma unroll
        for (int j = 0; j < 2; j++) {
            *(bf16x8*)&Ks[0][kr[j] * 72 + kc[j]] = kreg[j];
            *(bf16x8*)&Vs[0][kr[j] * 72 + kc[j]] = vreg[j];
        }
        __syncthreads();

        for (int t = 0; t <= qj; t++) {
            int cur = t & 1;
            if (t < qj) {
                int kvn = (t + 1) * 64;
#pragma unroll
                for (int j = 0; j < 2; j++) {
                    kreg[j] = *(const bf16x8*)&Kb[(size_t)(kvn + kr[j]) * HD + kc[j]];
                    vreg[j] = *(const bf16x8*)&Vtb[(size_t)kr[j] * NN + kvn + kc[j]];
                }
            }

            const bf16* Kcur = Ks[cur];
            const bf16* Vcur = Vs[cur];
            int kv0 = t * 64;
            bool diag = (t == qj);
#pragma unroll
            for (int mi = 0; mi < 2; mi++) {
                int ba = 2 * mi, bb = 2 * mi + 1;
                bf16x8 ka0 = *(const bf16x8*)&Kcur[(ba * 16 + l16) * 72 + quad * 8];
                bf16x8 ka1 = *(const bf16x8*)&Kcur[(ba * 16 + l16) * 72 + 32 + quad * 8];
                bf16x8 kb0 = *(const bf16x8*)&Kcur[(bb * 16 + l16) * 72 + quad * 8];
                bf16x8 kb1 = *(const bf16x8*)&Kcur[(bb * 16 + l16) * 72 + 32 + quad * 8];
                f32x4 sa = (f32x4){0.f, 0.f, 0.f, 0.f};
                f32x4 sb = (f32x4){0.f, 0.f, 0.f, 0.f};
                sa = __builtin_amdgcn_mfma_f32_16x16x32_bf16(ka0, qf[0], sa, 0, 0, 0);
                sa = __builtin_amdgcn_mfma_f32_16x16x32_bf16(ka1, qf[1], sa, 0, 0, 0);
                sb = __builtin_amdgcn_mfma_f32_16x16x32_bf16(kb0, qf[0], sb, 0, 0, 0);
                sb = __builtin_amdgcn_mfma_f32_16x16x32_bf16(kb1, qf[1], sb, 0, 0, 0);
                bf16x4 pa4, pb4;
                if (diag) {
                    int kva = kv0 + ba * 16 + quad * 4;
                    int kvb = kv0 + bb * 16 + quad * 4;
#pragma unroll
                    for (int r = 0; r < 4; r++) {
                        pa4[r] = (bf16)((kva + r > qrow) ? 0.f : exp2f(sa[r]));
                        pb4[r] = (bf16)((kvb + r > qrow) ? 0.f : exp2f(sb[r]));
                    }
                } else {
#pragma unroll
                    for (int r = 0; r < 4; r++) {
                        pa4[r] = (bf16)exp2f(sa[r]);
                        pb4[r] = (bf16)exp2f(sb[r]);
                    }
                }
                bf16x8 pfrag = __builtin_shufflevector(pa4, pb4, 0, 1, 2, 3, 4, 5, 6, 7);
                l_sum = __builtin_amdgcn_mfma_f32_16x16x32_bf16(pfrag, ones8, l_sum, 0, 0, 0);
#pragma unroll
                for (int di = 0; di < 4; di++) {
                    bf16x8 vfrag = *(const bf16x8*)&Vcur[(di * 16 + l16) * 72 + mi * 32 + quad * 8];
                    o_acc[di] = __builtin_amdgcn_mfma_f32_16x16x32_bf16(pfrag, vfrag, o_acc[di], 0, 0, 0);
                }
            }

            if (t < qj) {
                bf16* Kn = Ks[cur ^ 1];
                bf16* Vn = Vs[cur ^ 1];
#pragma unroll
                for (int j = 0; j < 2; j++) {
                    *(bf16x8*)&Kn[kr[j] * 72 + kc[j]] = kreg[j];
                    *(bf16x8*)&Vn[kr[j] * 72 + kc[j]] = vreg[j];
                }
            }
            __syncthreads();
        }

        // Epilogue: O/l -> [B, N, H*HD] (concat-head layout for the O-proj GEMM)
#pragma unroll
        for (int r = 0; r < 4; r++) {
            float inv = 1.0f / l_sum[r];
            int tok = q0 + w * 16 + quad * 4 + r;
#pragma unroll
            for (int di = 0; di < 4; di++) {
                int d = h * 64 + di * 16 + l16;
                Oc[((size_t)(b * NN + tok)) * DD + d] = (bf16)(o_acc[di][r] * inv);
            }
        }
    }
}

// ---------------------------------------------------------------------------
extern "C" void kernel_launch(void* const* d_in, const int* in_sizes, int n_in,
                              void* d_out, int out_size, void* d_ws, size_t ws_size,
                              hipStream_t stream) {
    const float* x  = (const float*)d_in[0];
    const float* Wq = (const float*)d_in[1];
    const float* bq = (const float*)d_in[2];
    const float* Wk = (const float*)d_in[3];
    const float* bk = (const float*)d_in[4];
    const float* Wv = (const float*)d_in[5];
    const float* bv = (const float*)d_in[6];
    const float* Wo = (const float*)d_in[7];
    const float* bo = (const float*)d_in[8];

    const size_t need = (size_t)(8388608ull * 5 + 4194304ull) * sizeof(bf16);
    if (ws_size < need) return; // diagnostic: leaves d_out zeroed (absmax 3.8125)

    bf16* ws = (bf16*)d_ws;
    bf16* xb = ws;
    bf16* wt = xb + (size_t)MM * DD;
    bf16* Qw = wt + 4ull * DD * DD;       // [B*H, N, HD], pre-scaled 0.125*log2e
    bf16* Kw = Qw + (size_t)MM * DD;      // [B*H, N, HD]
    bf16* Vw = Kw + (size_t)MM * DD;      // V^T [B*H, HD, N], kv-permuted
    bf16* Aw = Vw + (size_t)MM * DD;      // attention out [B, N, D]

    prep<<<dim3(4096, 1, 2), 256, 0, stream>>>(x, Wq, Wk, Wv, Wo, xb, wt);

    // 256x128 tiles: 768 blocks = exactly 3/CU, 24 waves/CU throughout.
    gemm_qkv<<<dim3(MM / 256, DD / 128, 3), 512, 0, stream>>>(
        xb, wt, bq, bk, bv, Qw, Kw, Vw);

    // grid (bh, 16): bh%8 -> XCD affinity; paired qj/31-qj -> every block
    // exactly 33 kv-iters; 1024 blocks x 36864B LDS = exactly 4 blocks/CU.
    flash_attn<<<dim3(BB * HH, 16), 256, 0, stream>>>(Qw, Kw, Vw, Aw);

    gemm_out<<<dim3(MM / 128, DD / 128), 256, 0, stream>>>(
        Aw, wt + 3ull * DD * DD, bo, (float*)d_out);
}

// Round 13
// 264.960 us; speedup vs baseline: 2.2937x; 2.2937x over previous
//
#include <hip/hip_runtime.h>
#include <hip/hip_bf16.h>

// MultiHeadAttention: B=4, N=2048, D=1024, H=16, HD=64, causal.
// Contract: f32 inputs AND f32 output; bf16 internal compute.
// R22 = R21 with ONE change: gemm_qkv launch_bounds (512,6) -> (512,4).
// R21's forced 6-waves/EU bound (~85 VGPR cap) caused a spill storm
// (VGPR 40, WRITE 1.29GB scratch, 417us) — same failure mode as R12.
// Rule (twice learned): never force occupancy via the min-waves arg; cap
// at 128 (4/EU) and let the allocator breathe. The 256x128-tile design
// itself passed correctness and is now actually measured for the first
// time. At the expected ~80-84 VGPR: 6 waves/SIMD -> 3 blocks/CU ->
// grid 768 = one full round, zero residency tail.

#define BB 4
#define NN 2048
#define DD 1024
#define HH 16
#define HD 64
#define MM (BB * NN) // 8192

typedef __bf16 bf16;
typedef __bf16 bf16x4 __attribute__((ext_vector_type(4)));
typedef __bf16 bf16x8 __attribute__((ext_vector_type(8)));
typedef float f32x4 __attribute__((ext_vector_type(4)));

// Async 16B global->LDS copy. LDS dest must follow wave-uniform base + lane*16.
__device__ __forceinline__ void async_copy16(bf16* lds, const bf16* g) {
    __builtin_amdgcn_global_load_lds(
        (const __attribute__((address_space(1))) void*)g,
        (__attribute__((address_space(3))) void*)lds, 16, 0, 0);
}

// ---------------------------------------------------------------------------
// prep: fused input conversion + weight transpose (one dispatch, z = role).
// ---------------------------------------------------------------------------
__global__ void prep(const float* __restrict__ x,
                     const float* __restrict__ W0, const float* __restrict__ W1,
                     const float* __restrict__ W2, const float* __restrict__ W3,
                     bf16* __restrict__ xb, bf16* __restrict__ Wt) {
    __shared__ float tile[32][33];
    if (blockIdx.z == 0) {
        int i = (blockIdx.x * 256 + threadIdx.x) * 8;
        float4 a = *(const float4*)&x[i];
        float4 b = *(const float4*)&x[i + 4];
        bf16x8 o;
        o[0] = (bf16)a.x; o[1] = (bf16)a.y; o[2] = (bf16)a.z; o[3] = (bf16)a.w;
        o[4] = (bf16)b.x; o[5] = (bf16)b.y; o[6] = (bf16)b.z; o[7] = (bf16)b.w;
        *(bf16x8*)&xb[i] = o;
    } else {
        int wz = blockIdx.x >> 10;            // 0..3
        int by = (blockIdx.x >> 5) & 31;
        int bx = blockIdx.x & 31;
        const float* W = (wz == 0) ? W0 : (wz == 1) ? W1 : (wz == 2) ? W2 : W3;
        bf16* out = Wt + (size_t)wz * DD * DD;
        int tx = threadIdx.x & 31, ty = threadIdx.x >> 5; // 32 x 8
        int x0 = bx * 32, y0 = by * 32;
#pragma unroll
        for (int i = 0; i < 32; i += 8)
            tile[ty + i][tx] = W[(size_t)(y0 + ty + i) * DD + x0 + tx];
        __syncthreads();
#pragma unroll
        for (int i = 0; i < 32; i += 8)
            out[(size_t)(x0 + ty + i) * DD + y0 + tx] = (bf16)tile[tx][ty + i];
    }
}

// ---------------------------------------------------------------------------
// gemm_qkv: C[256x128 tile] = A[M,K] * Wt[N,K]^T + bias, bf16 MFMA, BK=32.
// 512 threads = 8 waves in 4(m) x 2(n); each wave 64x64 (4x4 MFMA 16x16x32).
// grid (32, 8, 3): z selects Q/K/V. Q scaled by 0.125*log2e.
// z==0/1: bf16 out [B*H, N, HD]; z==2: V^T out [B*H, HD, N], kv-permuted
// per-32-tok: pos p <- orig o(p) = (p>>3)*4 + ((p>>2)&1)*16 + (p&3).
// Epilogue: two 128-row passes via Cs[128][136] (aliased over As/Bs).
// ---------------------------------------------------------------------------
__global__ __launch_bounds__(512, 4) void gemm_qkv(
    const bf16* __restrict__ A, const bf16* __restrict__ Wt,
    const float* __restrict__ b0, const float* __restrict__ b1,
    const float* __restrict__ b2, bf16* __restrict__ out0,
    bf16* __restrict__ out1, bf16* __restrict__ out2) {
    const int K = DD;
    // Union: K-loop uses As(8192 elems) + Bs(4096); epilogue uses Cs(17408).
    __shared__ __align__(16) bf16 smem[128 * 136];
    bf16* As = smem;               // [256][32]
    bf16* Bs = smem + 256 * 32;    // [128][32]
    bf16* Cs = smem;               // epilogue alias, [128][136]

    int m0 = blockIdx.x * 256;
    int n0 = blockIdx.y * 128;
    int z = blockIdx.z;
    const bf16* Wz = Wt + (size_t)z * DD * DD;
    const float* bias = (z == 0) ? b0 : ((z == 1) ? b1 : b2);
    bf16* out = (z == 0) ? out0 : ((z == 1) ? out1 : out2);
    float scale = (z == 0) ? 0.125f * 1.44269504f : 1.0f;

    int tid = threadIdx.x;
    int w = tid >> 6, lane = tid & 63;
    int wm = w >> 1, wn = w & 1;          // wm 0..3, wn 0..1
    int quad = lane >> 4, l16 = lane & 15;

    f32x4 acc[4][4];
#pragma unroll
    for (int i = 0; i < 4; i++)
#pragma unroll
        for (int j = 0; j < 4; j++) acc[i][j] = (f32x4){0.f, 0.f, 0.f, 0.f};

    for (int k0 = 0; k0 < K; k0 += 32) {
        __syncthreads(); // previous iteration's LDS reads complete
        // A: 1024 chunks (2/thread); B: 512 chunks (1/thread). Linear dests.
#pragma unroll
        for (int j = 0; j < 2; j++) {
            int c = j * 512 + tid;
            int row = c >> 2, kk = (c & 3) * 8;
            async_copy16(&As[c * 8], &A[(size_t)(m0 + row) * K + k0 + kk]);
        }
        {
            int row = tid >> 2, kk = (tid & 3) * 8;
            async_copy16(&Bs[tid * 8], &Wz[(size_t)(n0 + row) * K + k0 + kk]);
        }
        __syncthreads(); // drains vmcnt(0) before barrier

        bf16x8 af[4], bfm[4];
#pragma unroll
        for (int i = 0; i < 4; i++) {
            af[i] = *(const bf16x8*)&As[(wm * 64 + i * 16 + l16) * 32 + quad * 8];
            bfm[i] = *(const bf16x8*)&Bs[(wn * 64 + i * 16 + l16) * 32 + quad * 8];
        }
#pragma unroll
        for (int i = 0; i < 4; i++)
#pragma unroll
            for (int j = 0; j < 4; j++)
                acc[i][j] = __builtin_amdgcn_mfma_f32_16x16x32_bf16(
                    af[i], bfm[j], acc[i][j], 0, 0, 0);
    }

    // Epilogue. C/D layout: col(n) = l16, row(m) = quad*4 + reg.
    int bidx = m0 >> 11;          // batch (256-row tile never crosses batch)
    int tok0 = m0 & (NN - 1);
    int hh0 = n0 >> 6;            // first of the 2 heads this tile covers
    __syncthreads();              // all waves' As/Bs reads done

#pragma unroll
    for (int pp = 0; pp < 2; pp++) {
        if (pp) __syncthreads();  // previous pass's stores done before restage
        // Stage: waves with wm>>1 == pp hold rows pp*128 .. pp*128+127.
        if ((wm >> 1) == pp) {
#pragma unroll
            for (int j = 0; j < 4; j++) {
                int nl = wn * 64 + j * 16 + l16;
                float bv = bias[n0 + nl];
#pragma unroll
                for (int i = 0; i < 4; i++) {
#pragma unroll
                    for (int r = 0; r < 4; r++) {
                        int mloc = (wm & 1) * 64 + i * 16 + quad * 4 + r; // 0..127
                        bf16 v = (bf16)((acc[i][j][r] + bv) * scale);
                        if (z == 2) Cs[nl * 136 + mloc] = v;
                        else        Cs[mloc * 136 + nl] = v;
                    }
                }
            }
        }
        __syncthreads();

        if (z != 2) {
            // out [bh][tok][hd]: tokens tok0+pp*128..+128, both heads.
#pragma unroll
            for (int hf = 0; hf < 2; hf++) {
                bf16* base = out +
                    ((size_t)(bidx * HH + hh0 + hf) * NN + tok0 + pp * 128) * HD;
#pragma unroll
                for (int k = 0; k < 2; k++) {
                    int f = k * 4096 + tid * 8;       // 0..8191; tok=f>>6, hd=f&63
                    *(bf16x8*)&base[f] =
                        *(const bf16x8*)&Cs[(f >> 6) * 136 + hf * 64 + (f & 63)];
                }
            }
        } else {
            // V^T out [bh][hd][tok], kv-permuted per 32-tok block.
#pragma unroll
            for (int k = 0; k < 4; k++) {
                int idx = k * 4096 + tid * 8;         // 0..16383
                int nl = idx >> 7;                    // 0..127
                int p0 = idx & 127;                   // 8-aligned
                int hf = nl >> 6, hd = nl & 63;
                int base32 = p0 & ~31;
                int qq = (p0 & 31) >> 3;
                const bf16* crow = &Cs[nl * 136];
                bf16x4 lo = *(const bf16x4*)&crow[base32 + qq * 4];
                bf16x4 hi = *(const bf16x4*)&crow[base32 + qq * 4 + 16];
                bf16x8 v = __builtin_shufflevector(lo, hi, 0, 1, 2, 3, 4, 5, 6, 7);
                bf16* dst = out +
                    ((size_t)(bidx * HH + hh0 + hf) * HD + hd) * NN +
                    tok0 + pp * 128 + p0;
                *(bf16x8*)dst = v;
            }
        }
    }
}

// ---------------------------------------------------------------------------
// gemm_out: out-projection, f32 output, plain [M, N]. 128x128 tile, 4 waves,
// BK=32 (unchanged measured-best structure; 512 blocks = single-round).
// ---------------------------------------------------------------------------
__global__ __launch_bounds__(256) void gemm_out(
    const bf16* __restrict__ A, const bf16* __restrict__ Wt,
    const float* __restrict__ bias, float* __restrict__ out) {
    const int K = DD;
    __shared__ __align__(16) bf16 smem[128 * 64];
    bf16* As = smem;
    bf16* Bs = smem + 128 * 32;

    int m0 = blockIdx.x * 128;
    int n0 = blockIdx.y * 128;

    int tid = threadIdx.x;
    int w = tid >> 6, lane = tid & 63;
    int wm = w >> 1, wn = w & 1;
    int quad = lane >> 4, l16 = lane & 15;

    f32x4 acc[4][4];
#pragma unroll
    for (int i = 0; i < 4; i++)
#pragma unroll
        for (int j = 0; j < 4; j++) acc[i][j] = (f32x4){0.f, 0.f, 0.f, 0.f};

    for (int k0 = 0; k0 < K; k0 += 32) {
        __syncthreads();
#pragma unroll
        for (int j = 0; j < 2; j++) {
            int c = j * 256 + w * 64 + lane;
            int row = c >> 2, kk = (c & 3) * 8;
            async_copy16(&As[c * 8], &A[(size_t)(m0 + row) * K + k0 + kk]);
            async_copy16(&Bs[c * 8], &Wt[(size_t)(n0 + row) * K + k0 + kk]);
        }
        __syncthreads();

        bf16x8 af[4], bfm[4];
#pragma unroll
        for (int i = 0; i < 4; i++) {
            af[i] = *(const bf16x8*)&As[(wm * 64 + i * 16 + l16) * 32 + quad * 8];
            bfm[i] = *(const bf16x8*)&Bs[(wn * 64 + i * 16 + l16) * 32 + quad * 8];
        }
#pragma unroll
        for (int i = 0; i < 4; i++)
#pragma unroll
            for (int j = 0; j < 4; j++)
                acc[i][j] = __builtin_amdgcn_mfma_f32_16x16x32_bf16(
                    af[i], bfm[j], acc[i][j], 0, 0, 0);
    }

#pragma unroll
    for (int j = 0; j < 4; j++) {
        int n = n0 + wn * 64 + j * 16 + l16;
        float bv = bias[n];
#pragma unroll
        for (int i = 0; i < 4; i++) {
            int mrow = m0 + wm * 64 + i * 16 + quad * 4;
#pragma unroll
            for (int r = 0; r < 4; r++)
                out[(size_t)(mrow + r) * DD + n] = acc[i][j][r] + bv;
        }
    }
}

// ---------------------------------------------------------------------------
// Flash attention (causal, no-max softmax) — R20 (kept): fine-grained blocks.
// grid = (B*H, 16), block = 256 threads (4 waves x 16 q-rows = 64-row q-tile).
// bh on blockIdx.x -> linear id%8 == bh%8 -> XCD L2 affinity for K/V.
// Block does q-tiles j=blockIdx.y and 31-blockIdx.y: 33 kv-iters per block;
// 1024 blocks x 36864B LDS = exactly 4/CU (4 independent barrier domains).
// ---------------------------------------------------------------------------
__global__ __launch_bounds__(256, 4) void flash_attn(
    const bf16* __restrict__ Q, const bf16* __restrict__ Kg,
    const bf16* __restrict__ Vt_g, bf16* __restrict__ Oc) {
    __shared__ __align__(16) bf16 Ks[2][64 * 72];   // [kv][hd], stride 72
    __shared__ __align__(16) bf16 Vs[2][64 * 72];   // [d][kv-perm], stride 72

    int bh = blockIdx.x;              // linear id % 8 == bh % 8 -> XCD locality
    int b = bh >> 4, h = bh & 15;
    int tid = threadIdx.x;
    int w = tid >> 6, lane = tid & 63;
    int quad = lane >> 4, l16 = lane & 15;

    const bf16* Qb = Q + (size_t)bh * NN * HD;
    const bf16* Kb = Kg + (size_t)bh * NN * HD;
    const bf16* Vtb = Vt_g + (size_t)bh * HD * NN;

    bf16x8 ones8;
#pragma unroll
    for (int i = 0; i < 8; i++) ones8[i] = (bf16)1.0f;

    int kr[2], kc[2];
#pragma unroll
    for (int j = 0; j < 2; j++) {
        int c = j * 256 + tid;
        kr[j] = c >> 3; kc[j] = (c & 7) * 8;   // row 0..63, col-chunk
    }

    for (int phase = 0; phase < 2; phase++) {
        int qj = (phase == 0) ? blockIdx.y : (31 - blockIdx.y);
        int q0 = qj * 64;
        int qrow = q0 + w * 16 + l16;

        bf16x8 qf[2];
#pragma unroll
        for (int ks = 0; ks < 2; ks++)
            qf[ks] = *(const bf16x8*)&Qb[(size_t)qrow * HD + ks * 32 + quad * 8];

        f32x4 l_sum = (f32x4){0.f, 0.f, 0.f, 0.f};
        f32x4 o_acc[4];
#pragma unroll
        for (int di = 0; di < 4; di++) o_acc[di] = (f32x4){0.f, 0.f, 0.f, 0.f};

        bf16x8 kreg[2], vreg[2];
#pragma unroll
        for (int j = 0; j < 2; j++) {
            kreg[j] = *(const bf16x8*)&Kb[(size_t)kr[j] * HD + kc[j]];
            vreg[j] = *(const bf16x8*)&Vtb[(size_t)kr[j] * NN + kc[j]];
        }
#pragma unroll
        for (int j = 0; j < 2; j++) {
            *(bf16x8*)&Ks[0][kr[j] * 72 + kc[j]] = kreg[j];
            *(bf16x8*)&Vs[0][kr[j] * 72 + kc[j]] = vreg[j];
        }
        __syncthreads();

        for (int t = 0; t <= qj; t++) {
            int cur = t & 1;
            if (t < qj) {
                int kvn = (t + 1) * 64;
#pragma unroll
                for (int j = 0; j < 2; j++) {
                    kreg[j] = *(const bf16x8*)&Kb[(size_t)(kvn + kr[j]) * HD + kc[j]];
                    vreg[j] = *(const bf16x8*)&Vtb[(size_t)kr[j] * NN + kvn + kc[j]];
                }
            }

            const bf16* Kcur = Ks[cur];
            const bf16* Vcur = Vs[cur];
            int kv0 = t * 64;
            bool diag = (t == qj);
#pragma unroll
            for (int mi = 0; mi < 2; mi++) {
                int ba = 2 * mi, bb = 2 * mi + 1;
                bf16x8 ka0 = *(const bf16x8*)&Kcur[(ba * 16 + l16) * 72 + quad * 8];
                bf16x8 ka1 = *(const bf16x8*)&Kcur[(ba * 16 + l16) * 72 + 32 + quad * 8];
                bf16x8 kb0 = *(const bf16x8*)&Kcur[(bb * 16 + l16) * 72 + quad * 8];
                bf16x8 kb1 = *(const bf16x8*)&Kcur[(bb * 16 + l16) * 72 + 32 + quad * 8];
                f32x4 sa = (f32x4){0.f, 0.f, 0.f, 0.f};
                f32x4 sb = (f32x4){0.f, 0.f, 0.f, 0.f};
                sa = __builtin_amdgcn_mfma_f32_16x16x32_bf16(ka0, qf[0], sa, 0, 0, 0);
                sa = __builtin_amdgcn_mfma_f32_16x16x32_bf16(ka1, qf[1], sa, 0, 0, 0);
                sb = __builtin_amdgcn_mfma_f32_16x16x32_bf16(kb0, qf[0], sb, 0, 0, 0);
                sb = __builtin_amdgcn_mfma_f32_16x16x32_bf16(kb1, qf[1], sb, 0, 0, 0);
                bf16x4 pa4, pb4;
                if (diag) {
                    int kva = kv0 + ba * 16 + quad * 4;
                    int kvb = kv0 + bb * 16 + quad * 4;
#pragma unroll
                    for (int r = 0; r < 4; r++) {
                        pa4[r] = (bf16)((kva + r > qrow) ? 0.f : exp2f(sa[r]));
                        pb4[r] = (bf16)((kvb + r > qrow) ? 0.f : exp2f(sb[r]));
                    }
                } else {
#pragma unroll
                    for (int r = 0; r < 4; r++) {
                        pa4[r] = (bf16)exp2f(sa[r]);
                        pb4[r] = (bf16)exp2f(sb[r]);
                    }
                }
                bf16x8 pfrag = __builtin_shufflevector(pa4, pb4, 0, 1, 2, 3, 4, 5, 6, 7);
                l_sum = __builtin_amdgcn_mfma_f32_16x16x32_bf16(pfrag, ones8, l_sum, 0, 0, 0);
#pragma unroll
                for (int di = 0; di < 4; di++) {
                    bf16x8 vfrag = *(const bf16x8*)&Vcur[(di * 16 + l16) * 72 + mi * 32 + quad * 8];
                    o_acc[di] = __builtin_amdgcn_mfma_f32_16x16x32_bf16(pfrag, vfrag, o_acc[di], 0, 0, 0);
                }
            }

            if (t < qj) {
                bf16* Kn = Ks[cur ^ 1];
                bf16* Vn = Vs[cur ^ 1];
#pragma unroll
                for (int j = 0; j < 2; j++) {
                    *(bf16x8*)&Kn[kr[j] * 72 + kc[j]] = kreg[j];
                    *(bf16x8*)&Vn[kr[j] * 72 + kc[j]] = vreg[j];
                }
            }
            __syncthreads();
        }

        // Epilogue: O/l -> [B, N, H*HD] (concat-head layout for the O-proj GEMM)
#pragma unroll
        for (int r = 0; r < 4; r++) {
            float inv = 1.0f / l_sum[r];
            int tok = q0 + w * 16 + quad * 4 + r;
#pragma unroll
            for (int di = 0; di < 4; di++) {
                int d = h * 64 + di * 16 + l16;
                Oc[((size_t)(b * NN + tok)) * DD + d] = (bf16)(o_acc[di][r] * inv);
            }
        }
    }
}

// ---------------------------------------------------------------------------
extern "C" void kernel_launch(void* const* d_in, const int* in_sizes, int n_in,
                              void* d_out, int out_size, void* d_ws, size_t ws_size,
                              hipStream_t stream) {
    const float* x  = (const float*)d_in[0];
    const float* Wq = (const float*)d_in[1];
    const float* bq = (const float*)d_in[2];
    const float* Wk = (const float*)d_in[3];
    const float* bk = (const float*)d_in[4];
    const float* Wv = (const float*)d_in[5];
    const float* bv = (const float*)d_in[6];
    const float* Wo = (const float*)d_in[7];
    const float* bo = (const float*)d_in[8];

    const size_t need = (size_t)(8388608ull * 5 + 4194304ull) * sizeof(bf16);
    if (ws_size < need) return; // diagnostic: leaves d_out zeroed (absmax 3.8125)

    bf16* ws = (bf16*)d_ws;
    bf16* xb = ws;
    bf16* wt = xb + (size_t)MM * DD;
    bf16* Qw = wt + 4ull * DD * DD;       // [B*H, N, HD], pre-scaled 0.125*log2e
    bf16* Kw = Qw + (size_t)MM * DD;      // [B*H, N, HD]
    bf16* Vw = Kw + (size_t)MM * DD;      // V^T [B*H, HD, N], kv-permuted
    bf16* Aw = Vw + (size_t)MM * DD;      // attention out [B, N, D]

    prep<<<dim3(4096, 1, 2), 256, 0, stream>>>(x, Wq, Wk, Wv, Wo, xb, wt);

    // 256x128 tiles: 768 blocks; at ~80 VGPR -> 3 blocks/CU, one full round.
    gemm_qkv<<<dim3(MM / 256, DD / 128, 3), 512, 0, stream>>>(
        xb, wt, bq, bk, bv, Qw, Kw, Vw);

    // grid (bh, 16): bh%8 -> XCD affinity; paired qj/31-qj -> every block
    // exactly 33 kv-iters; 1024 blocks x 36864B LDS = exactly 4 blocks/CU.
    flash_attn<<<dim3(BB * HH, 16), 256, 0, stream>>>(Qw, Kw, Vw, Aw);

    gemm_out<<<dim3(MM / 128, DD / 128), 256, 0, stream>>>(
        Aw, wt + 3ull * DD * DD, bo, (float*)d_out);
}